// Round 11
// baseline (38.175 us; speedup 1.0000x reference)
//
#include <hip/hip_runtime.h>

#define ALPHA 0.2f
#define BATCH 16
#define WIN 100
#define KN 128          // nodes
#define DE 200          // embed dim
#define IT 8            // i-tile per block
#define DSL 25          // d-slice per wave-pair (8 x 25 = 200)
#define WCH 25          // w-chunk in phase A (4 chunks)

typedef float v2f __attribute__((ext_vector_type(2)));

// Single fused kernel. Block (b, i-tile): recompute Rt slice in REGISTERS
// (16x redundancy on right-GEMM, buys: 1 dispatch, no node drain, no global
// round-trip). All register arrays strictly compile-time indexed (rule #20).
__global__ __launch_bounds__(1024) void k_gat(
    const float* __restrict__ in, const float* __restrict__ lw,
    const float* __restrict__ lb, const float* __restrict__ aw,
    float* __restrict__ out) {
  int blk = blockIdx.x;
  int b = blk >> 4, it = blk & 15, i0 = it * IT;
  int t = threadIdx.x;
  int j = t & (KN - 1);
  int dh = t >> 7;
  int db = __builtin_amdgcn_readfirstlane(dh * DSL);

  __shared__ float Lis[DE][IT];       // [d][ii], 32B rows (broadcast reads)
  __shared__ float part[8][IT][KN];
  __shared__ float part_r[8][KN];
  __shared__ float ats[IT][132];

  // --- Phase B: Li for this block's 8 i's ---
  for (int idx = t; idx < IT * DE; idx += 1024) {
    int ii = idx / DE;                // consecutive idx -> consecutive d
    int d = idx - ii * DE;
    const float* xc = in + (size_t)b * WIN * KN + i0 + ii;
    const float* lc = lw + d;
    float a = 0.f;
#pragma unroll 4
    for (int w = 0; w < WIN; ++w)
      a = fmaf(xc[w * KN], lc[w * DE], a);
    Lis[d][ii] = a;
  }

  // --- Phase A: Rt slice in registers, chunked prefetch (25 loads in flight) ---
  float rt[DSL];
#pragma unroll
  for (int k = 0; k < DSL; ++k) rt[k] = 0.f;
  {
    const float* xcol = in + (size_t)b * WIN * KN + j;
    const float* lwr = lw + (size_t)WIN * DE + db;   // wave-uniform -> s_load
    for (int wc = 0; wc < WIN; wc += WCH) {
      float xv[WCH];
#pragma unroll
      for (int u = 0; u < WCH; ++u)
        xv[u] = xcol[(size_t)(wc + u) * KN];         // 25 coalesced loads in flight
#pragma unroll
      for (int u = 0; u < WCH; ++u) {
        const float* wrow = lwr + (size_t)(wc + u) * DE;
#pragma unroll
        for (int k = 0; k < DSL; ++k)
          rt[k] = fmaf(xv[u], wrow[k], rt[k]);
      }
    }
#pragma unroll
    for (int k = 0; k < DSL; ++k) rt[k] += lb[db + k];
  }

  __syncthreads();

  // --- Phase C: e-partials; rt in VGPRs (FULL unroll), Li broadcast via LDS ---
  {
    v2f acc0 = 0.f, acc1 = 0.f, acc2 = 0.f, acc3 = 0.f;
    float racc = 0.f;
#pragma unroll
    for (int k = 0; k < DSL; ++k) {
      int d = db + k;
      float r = rt[k];
      float a = aw[d];                               // uniform -> s_load
      float4 L0 = *reinterpret_cast<const float4*>(&Lis[d][0]);
      float4 L1 = *reinterpret_cast<const float4*>(&Lis[d][4]);
      racc = fmaf(r, a, racc);
      v2f rv = {r, r}, av = {a, a}, z = 0.f;
      v2f p0 = (v2f){L0.x, L0.y} + rv;
      v2f p1 = (v2f){L0.z, L0.w} + rv;
      v2f p2 = (v2f){L1.x, L1.y} + rv;
      v2f p3 = (v2f){L1.z, L1.w} + rv;
      p0 = __builtin_elementwise_min(p0, z);
      p1 = __builtin_elementwise_min(p1, z);
      p2 = __builtin_elementwise_min(p2, z);
      p3 = __builtin_elementwise_min(p3, z);
      acc0 += p0 * av; acc1 += p1 * av; acc2 += p2 * av; acc3 += p3 * av;
    }
    part[dh][0][j] = acc0.x; part[dh][1][j] = acc0.y;
    part[dh][2][j] = acc1.x; part[dh][3][j] = acc1.y;
    part[dh][4][j] = acc2.x; part[dh][5][j] = acc2.y;
    part[dh][6][j] = acc3.x; part[dh][7][j] = acc3.y;
    part_r[dh][j] = racc;
  }
  __syncthreads();

  // --- softmax: wave r (r<8) owns row r; e = ra - 0.8*M (shift-invariant) ---
  {
    int wid = t >> 6;
    if (wid < IT) {
      int r = wid, l = t & 63;
      float ra0 = 0.f, ra1 = 0.f, m0 = 0.f, m1 = 0.f;
#pragma unroll
      for (int s = 0; s < 8; ++s) {
        ra0 += part_r[s][l];     ra1 += part_r[s][l + 64];
        m0  += part[s][r][l];    m1  += part[s][r][l + 64];
      }
      float e0 = fmaf(m0, -(1.f - ALPHA), ra0);
      float e1 = fmaf(m1, -(1.f - ALPHA), ra1);
      float m = fmaxf(e0, e1);
      for (int off = 32; off; off >>= 1) m = fmaxf(m, __shfl_xor(m, off));
      float p0 = __expf(e0 - m), p1 = __expf(e1 - m);
      float s2 = p0 + p1;
      for (int off = 32; off; off >>= 1) s2 += __shfl_xor(s2, off);
      float inv = 1.f / s2;
      ats[r][l] = p0 * inv;
      ats[r][l + 64] = p1 * inv;
    }
  }
  __syncthreads();

  // --- PV: thread (w, q<8): out[b][w][i0+q]; x rows from global (L1-shared) ---
  if (t < 8 * WIN) {
    int w = t >> 3, q = t & 7;
    const float* xw = in + ((size_t)b * WIN + w) * KN;
    const float* ap = &ats[q][0];
    float s = 0.f;
#pragma unroll 8
    for (int jj = 0; jj < KN; jj += 4) {
      float4 x4 = *reinterpret_cast<const float4*>(xw + jj);
      float4 aa = *reinterpret_cast<const float4*>(ap + jj);
      s = fmaf(aa.x, x4.x, s); s = fmaf(aa.y, x4.y, s);
      s = fmaf(aa.z, x4.z, s); s = fmaf(aa.w, x4.w, s);
    }
    out[((size_t)b * WIN + w) * KN + i0 + q] = 1.f / (1.f + __expf(-s));
  }
}

extern "C" void kernel_launch(void* const* d_in, const int* in_sizes, int n_in,
                              void* d_out, int out_size, void* d_ws, size_t ws_size,
                              hipStream_t stream) {
  const float* in = (const float*)d_in[0];   // (16,100,128)
  const float* lw = (const float*)d_in[1];   // (200,200)
  const float* lb = (const float*)d_in[2];   // (200,)
  const float* aw = (const float*)d_in[3];   // (200,)
  float* out = (float*)d_out;                // (16,100,128)

  k_gat<<<BATCH * 16, 1024, 0, stream>>>(in, lw, lb, aw, out);
}

// Round 12
// 23.984 us; speedup vs baseline: 1.5917x; 1.5917x over previous
//
#include <hip/hip_runtime.h>

#define ALPHA 0.2f
#define BATCH 16
#define WIN 100
#define KN 128          // nodes
#define DE 200          // embed dim
#define IT 8            // i-tile per k_attn block

typedef float v2f __attribute__((ext_vector_type(2)));

// Kernel A (round-7 proven, unchanged): grid 16b x 25dt, 256 thr, zero LDS.
// lane j = t&127, d-quad = dt*8 + (t>>7)*4 (scalar path via readfirstlane).
//   Rt[b][d][j] = sum_w x[w][j]*lw[100+w][d] + lb[d]
//   Lt[b][d][j] = sum_w x[w][j]*lw[w][d]
__global__ __launch_bounds__(256) void k_lin(
    const float* __restrict__ in, const float* __restrict__ lw,
    const float* __restrict__ lb, float* __restrict__ Rt, float* __restrict__ Lt) {
  int blk = blockIdx.x;
  int b = blk / 25, dt = blk % 25;
  int t = threadIdx.x;
  int j = t & (KN - 1);
  int dbase = __builtin_amdgcn_readfirstlane(dt * 8 + (t >> 7) * 4);
  const float* inb = in + (size_t)b * WIN * KN + j;
  const float* lwl = lw + dbase;
  const float* lwr = lw + WIN * DE + dbase;
  float la0 = 0, la1 = 0, la2 = 0, la3 = 0;
  float ra0 = 0, ra1 = 0, ra2 = 0, ra3 = 0;
#pragma unroll 10
  for (int w = 0; w < WIN; ++w) {
    float x = inb[w * KN];
    float4 wl = *reinterpret_cast<const float4*>(lwl + w * DE);
    float4 wr = *reinterpret_cast<const float4*>(lwr + w * DE);
    la0 = fmaf(x, wl.x, la0); la1 = fmaf(x, wl.y, la1);
    la2 = fmaf(x, wl.z, la2); la3 = fmaf(x, wl.w, la3);
    ra0 = fmaf(x, wr.x, ra0); ra1 = fmaf(x, wr.y, ra1);
    ra2 = fmaf(x, wr.z, ra2); ra3 = fmaf(x, wr.w, ra3);
  }
  float4 bb = *reinterpret_cast<const float4*>(lb + dbase);
  float* rp = Rt + ((size_t)b * DE + dbase) * KN + j;
  float* lp = Lt + ((size_t)b * DE + dbase) * KN + j;
  rp[0 * KN] = ra0 + bb.x; rp[1 * KN] = ra1 + bb.y;
  rp[2 * KN] = ra2 + bb.z; rp[3 * KN] = ra3 + bb.w;
  lp[0 * KN] = la0; lp[1 * KN] = la1; lp[2 * KN] = la2; lp[3 * KN] = la3;
}

// Kernel B: round-7 structure; ONLY change: Lt/aw staged into LDS (vector
// loads), e-phase reads them as conflict-free LDS broadcasts instead of
// K$-missing s_loads.
__global__ __launch_bounds__(1024) void k_attn_out(
    const float* __restrict__ in, const float* __restrict__ aw,
    const float* __restrict__ Rt, const float* __restrict__ Lt,
    float* __restrict__ out) {
  int blk = blockIdx.x;
  int b = blk >> 4, it = blk & 15;
  int i0 = it * IT;
  int t = threadIdx.x;
  __shared__ float Lis[DE][IT];        // [d][ii], 32B rows (broadcast reads)
  __shared__ float aws[DE];
  __shared__ float part[8][IT][KN];
  __shared__ float part_r[8][KN];
  __shared__ float ats[IT][132];

  // --- stage Lis (200 rows x 8 contiguous floats) + aws, parallel float4 ---
  {
    const float* ltb = Lt + (size_t)b * DE * KN + i0;
    if (t < 2 * DE) {                  // 400 threads, one float4 each
      int d = t >> 1, h = (t & 1) << 2;
      *reinterpret_cast<float4*>(&Lis[d][h]) =
          *reinterpret_cast<const float4*>(ltb + (size_t)d * KN + h);
    }
    if (t >= 512 && t < 512 + DE) aws[t - 512] = aw[t - 512];
  }
  __syncthreads();

  // --- e-phase: thread (j, dh) covers 25 d's for 8 i's ---
  {
    int j = t & (KN - 1);
    int dh = t >> 7;
    int db = __builtin_amdgcn_readfirstlane(dh * 25);
    const float* rtb = Rt + (size_t)b * DE * KN + j;
    v2f acc0 = 0.f, acc1 = 0.f, acc2 = 0.f, acc3 = 0.f;
    float racc = 0.f;
#pragma unroll 5
    for (int dd = 0; dd < 25; ++dd) {
      int d = db + dd;
      float r = rtb[(size_t)d * KN];
      float a = aws[d];                // uniform addr -> LDS broadcast
      float4 L0 = *reinterpret_cast<const float4*>(&Lis[d][0]);
      float4 L1 = *reinterpret_cast<const float4*>(&Lis[d][4]);
      racc = fmaf(r, a, racc);
      v2f rv = {r, r}, av = {a, a}, z = 0.f;
      v2f p0 = (v2f){L0.x, L0.y} + rv;
      v2f p1 = (v2f){L0.z, L0.w} + rv;
      v2f p2 = (v2f){L1.x, L1.y} + rv;
      v2f p3 = (v2f){L1.z, L1.w} + rv;
      p0 = __builtin_elementwise_min(p0, z);
      p1 = __builtin_elementwise_min(p1, z);
      p2 = __builtin_elementwise_min(p2, z);
      p3 = __builtin_elementwise_min(p3, z);
      acc0 += p0 * av; acc1 += p1 * av; acc2 += p2 * av; acc3 += p3 * av;
    }
    part[dh][0][j] = acc0.x; part[dh][1][j] = acc0.y;
    part[dh][2][j] = acc1.x; part[dh][3][j] = acc1.y;
    part[dh][4][j] = acc2.x; part[dh][5][j] = acc2.y;
    part[dh][6][j] = acc3.x; part[dh][7][j] = acc3.y;
    part_r[dh][j] = racc;
  }
  __syncthreads();

  // --- softmax: wave r (r<8) owns row r; e = ra - 0.8*M (shift-invariant) ---
  {
    int wid = t >> 6;
    if (wid < IT) {
      int r = wid, l = t & 63;
      float ra0 = 0.f, ra1 = 0.f, m0 = 0.f, m1 = 0.f;
#pragma unroll
      for (int s = 0; s < 8; ++s) {
        ra0 += part_r[s][l];     ra1 += part_r[s][l + 64];
        m0  += part[s][r][l];    m1  += part[s][r][l + 64];
      }
      float e0 = fmaf(m0, -(1.f - ALPHA), ra0);
      float e1 = fmaf(m1, -(1.f - ALPHA), ra1);
      float m = fmaxf(e0, e1);
      for (int off = 32; off; off >>= 1) m = fmaxf(m, __shfl_xor(m, off));
      float p0 = __expf(e0 - m), p1 = __expf(e1 - m);
      float s2 = p0 + p1;
      for (int off = 32; off; off >>= 1) s2 += __shfl_xor(s2, off);
      float inv = 1.f / s2;
      ats[r][l] = p0 * inv;
      ats[r][l + 64] = p1 * inv;
    }
  }
  __syncthreads();

  // --- PV: thread (w, q<8): out[b][w][i0+q]; x rows from global (L1-shared) ---
  if (t < 8 * WIN) {
    int w = t >> 3, q = t & 7;
    const float* xw = in + ((size_t)b * WIN + w) * KN;
    const float* ap = &ats[q][0];
    float s = 0.f;
#pragma unroll 8
    for (int jj = 0; jj < KN; jj += 4) {
      float4 x4 = *reinterpret_cast<const float4*>(xw + jj);
      float4 aa = *reinterpret_cast<const float4*>(ap + jj);
      s = fmaf(aa.x, x4.x, s); s = fmaf(aa.y, x4.y, s);
      s = fmaf(aa.z, x4.z, s); s = fmaf(aa.w, x4.w, s);
    }
    out[((size_t)b * WIN + w) * KN + i0 + q] = 1.f / (1.f + __expf(-s));
  }
}

extern "C" void kernel_launch(void* const* d_in, const int* in_sizes, int n_in,
                              void* d_out, int out_size, void* d_ws, size_t ws_size,
                              hipStream_t stream) {
  const float* in = (const float*)d_in[0];   // (16,100,128)
  const float* lw = (const float*)d_in[1];   // (200,200)
  const float* lb = (const float*)d_in[2];   // (200,)
  const float* aw = (const float*)d_in[3];   // (200,)
  float* out = (float*)d_out;                // (16,100,128)

  float* Rt = (float*)d_ws;                          // 16*200*128 floats (1.6 MB)
  float* Lt = Rt + (size_t)BATCH * DE * KN;          // 16*200*128 floats (1.6 MB)

  k_lin     <<<BATCH * 25, 256, 0, stream>>>(in, lw, lb, Rt, Lt);
  k_attn_out<<<BATCH * 16, 1024, 0, stream>>>(in, aw, Rt, Lt, out);
}